// Round 4
// baseline (2440.041 us; speedup 1.0000x reference)
//
#include <hip/hip_runtime.h>
#include <math.h>

#define B 2048
#define T 48
#define C 35
#define NUM 19
#define H 128
#define R 4              // batch rows per block -> 512 blocks -> 2 blocks/CU (VGPR<=128)
#define NBLK (B / R)     // 512 blocks
#define NTHR 512
#define K2C 70           // 2*C
#define K2C4 72          // padded to mult of 4
#define KG 198           // 2*C + H
#define KG4 200          // padded
#define C4 36            // C padded
#define G4 512           // 4*H
#define NO 665           // NUM*C

// ws layout (floats) — weight panels packed as k-blocked float4 tiles:
// w4[(k>>2)*(OUT*4) + out*4 + (k&3)]
#define WS_MSUM 0                        // [48] inv msum (padded to 64)
#define WS_WGT4 64                       // [KG4/4][G4][4] gates weights
#define WS_GB   (WS_WGT4 + KG4 * G4)     // [512] b_ih + b_hh
#define WS_WCT4 (WS_GB + G4)             // [K2C4/4][NO][4] w_comb
#define WS_WDH4 (WS_WCT4 + K2C4 * NO)    // [C4/4][H][4] w_dh
#define WS_WHR4 (WS_WDH4 + C4 * H)       // [H/4][C][4] w_hr
#define WS_FRT  (WS_WHR4 + H * C)        // [35][35] fr_w^T (zero diag), scalar

__global__ __launch_bounds__(256)
void prep_kernel(const float* __restrict__ mask,
                 const float* __restrict__ w_dh,
                 const float* __restrict__ w_hr,
                 const float* __restrict__ w_fr,
                 const float* __restrict__ w_comb,
                 const float* __restrict__ w_ih,
                 const float* __restrict__ w_hh,
                 const float* __restrict__ b_ih,
                 const float* __restrict__ b_hh,
                 float* __restrict__ ws,
                 float* __restrict__ out) {
    int blk = blockIdx.x, tid = threadIdx.x;
    if (blk < T) {
        // msum for timestep t = blk (sum over full batch)
        float s = 0.f;
        for (int i = tid; i < B * C; i += 256) {
            int b = i / C, c = i % C;
            s += mask[((size_t)b * T + blk) * C + c];
        }
        __shared__ float red[256];
        red[tid] = s;
        __syncthreads();
        for (int off = 128; off > 0; off >>= 1) {
            if (tid < off) red[tid] += red[tid + off];
            __syncthreads();
        }
        if (tid == 0) ws[WS_MSUM + blk] = 1.0f / (red[0] + 1e-5f);
    } else {
        int gt = (blk - T) * 256 + tid;  // 0..4095
        if (gt == 0) out[0] = 0.f;       // zero the loss accumulator
        // gates weights: k in [0,200), j in [0,512)
        for (int i = gt; i < KG4 * G4; i += 4096) {
            int k = i / G4, j = i % G4;
            float v = 0.f;
            if (k < K2C)      v = w_ih[j * K2C + k];
            else if (k < KG)  v = w_hh[j * H + (k - K2C)];
            ws[WS_WGT4 + (k >> 2) * (G4 * 4) + j * 4 + (k & 3)] = v;
        }
        for (int j = gt; j < G4; j += 4096) ws[WS_GB + j] = b_ih[j] + b_hh[j];
        // w_comb: f in [0,72), idx in [0,665)
        for (int i = gt; i < K2C4 * NO; i += 4096) {
            int f = i / NO, idx = i % NO;
            float v = (f < K2C) ? w_comb[idx * K2C + f] : 0.f;
            ws[WS_WCT4 + (f >> 2) * (NO * 4) + idx * 4 + (f & 3)] = v;
        }
        // w_dh: k in [0,36), j in [0,128)
        for (int i = gt; i < C4 * H; i += 4096) {
            int k = i / H, j = i % H;
            float v = (k < C) ? w_dh[j * C + k] : 0.f;
            ws[WS_WDH4 + (k >> 2) * (H * 4) + j * 4 + (k & 3)] = v;
        }
        // w_hr: k in [0,128), o in [0,35)
        for (int i = gt; i < H * C; i += 4096) {
            int k = i / C, o = i % C;
            ws[WS_WHR4 + (k >> 2) * (C * 4) + o * 4 + (k & 3)] = w_hr[o * H + k];
        }
        for (int i = gt; i < C * C; i += 4096) {
            int k = i / C, o = i % C;
            ws[WS_FRT + i] = (k == o) ? 0.f : w_fr[o * C + k];
        }
    }
}

__global__ __launch_bounds__(NTHR)
void main_kernel(const float* __restrict__ x, const float* __restrict__ mask,
                 const float* __restrict__ delta,
                 const float* __restrict__ b_dh, const float* __restrict__ w_dx,
                 const float* __restrict__ b_dx, const float* __restrict__ b_hr,
                 const float* __restrict__ b_fr, const float* __restrict__ b_comb,
                 const float* __restrict__ ws, float* __restrict__ out) {
    __shared__ float sh[R][H];       // hidden state
    __shared__ float scl[R][H];      // cell state
    __shared__ float sx[R][C];
    __shared__ float sdt[R][C4];     // delta (padded, [35]=0)
    __shared__ float scat[R][K2C4];  // [gamma_x | mask | 0,0]
    __shared__ float sv[R][KG4];     // [c_c | mask | h | 0,0] — P6 input vector
    __shared__ float sxh[R][C];
    __shared__ float sxc[R][C];
    __shared__ float szh[R][C];
    __shared__ float sbig[R * NUM * C];  // aliased: temp_h (P4-P5) / gates (P6-P7) / reduce

    float (*stemp)[NUM][C] = (float (*)[NUM][C])sbig;
    float (*sg)[G4] = (float (*)[G4])sbig;

    const int tid = threadIdx.x;
    const int b0 = blockIdx.x * R;
    const float4* Wg4 = (const float4*)(ws + WS_WGT4);
    const float*  gb  = ws + WS_GB;
    const float4* Wc4 = (const float4*)(ws + WS_WCT4);
    const float4* Wd4 = (const float4*)(ws + WS_WDH4);
    const float4* Wr4 = (const float4*)(ws + WS_WHR4);
    const float*  frT = ws + WS_FRT;
    float* imp = out + 1;
    float* ens = out + 1 + (size_t)B * T * C;

    for (int i = tid; i < R * H; i += NTHR) { ((float*)sh)[i] = 0.f; ((float*)scl)[i] = 0.f; }
    if (tid < R) {  // zero the pads once; never rewritten
        sdt[tid][C] = 0.f;
        scat[tid][K2C] = 0.f; scat[tid][K2C + 1] = 0.f;
        sv[tid][KG] = 0.f; sv[tid][KG + 1] = 0.f;
    }
    float loss = 0.f;
    __syncthreads();

    for (int t = 0; t < T; ++t) {
        const float inv_msum = ws[WS_MSUM + t];

        // P0: load x, mask, delta; gamma_x
        for (int i = tid; i < R * C; i += NTHR) {
            int r = i / C, c = i % C;
            size_t gi = ((size_t)(b0 + r) * T + t) * C + c;
            float xv = x[gi], mv = mask[gi], dv = delta[gi];
            sx[r][c] = xv; sdt[r][c] = dv;
            scat[r][c] = __expf(-fmaxf(dv * w_dx[c * C + c] + b_dx[c], 0.f));
            scat[r][C + c] = mv;
            sv[r][C + c] = mv;
        }
        __syncthreads();

        // P1: gamma_h, decay h; also mirror h into sv for P6
        for (int i = tid; i < R * H; i += NTHR) {
            int r = i / H, j = i % H;
            float d = b_dh[j];
            const float4* W = Wd4 + j;
            for (int kb = 0; kb < C4 / 4; ++kb) {
                float4 w = W[kb * H];
                float4 s = *(const float4*)&sdt[r][4 * kb];
                d += w.x * s.x; d += w.y * s.y; d += w.z * s.z; d += w.w * s.w;
            }
            float hv = sh[r][j] * __expf(-fmaxf(d, 0.f));
            sh[r][j] = hv;
            sv[r][K2C + j] = hv;
        }
        __syncthreads();

        // P2: x_h = h @ w_hr^T + b_hr; loss1; x_c
        float l_acc = 0.f;
        if (tid < R * C) {
            int r = tid / C, o = tid % C;
            float d = b_hr[o];
            const float4* W = Wr4 + o;
            for (int kb = 0; kb < H / 4; ++kb) {
                float4 w = W[kb * C];
                float4 s = *(const float4*)&sh[r][4 * kb];
                d += w.x * s.x; d += w.y * s.y; d += w.z * s.z; d += w.w * s.w;
            }
            float xv = sx[r][o], mv = scat[r][C + o];
            sxh[r][o] = d;
            l_acc += fabsf(xv - d) * mv;
            sxc[r][o] = mv * xv + (1.f - mv) * d;
        }
        __syncthreads();

        // P3: z_h = x_c @ fr_w^T + b_fr; loss2
        if (tid < R * C) {
            int r = tid / C, o = tid % C;
            float d = b_fr[o];
            for (int k = 0; k < C; ++k) d += frT[k * C + o] * sxc[r][k];
            szh[r][o] = d;
            l_acc += fabsf(sx[r][o] - d) * scat[r][C + o];
        }
        __syncthreads();

        // P4: alpha GEMM -> temp_h, quantile loss, ens write
        float ql = 0.f;
        for (int idx = tid; idx < NO; idx += NTHR) {
            int n = idx / C, o = idx % C;
            float q = 0.05f * (float)(n + 1);
            float acc[R];
            float bc = b_comb[idx];
#pragma unroll
            for (int r = 0; r < R; ++r) acc[r] = bc;
            const float4* W = Wc4 + idx;
            for (int fb = 0; fb < K2C4 / 4; ++fb) {
                float4 w = W[fb * NO];
#pragma unroll
                for (int r = 0; r < R; ++r) {
                    float4 s = *(const float4*)&scat[r][4 * fb];
                    acc[r] += w.x * s.x; acc[r] += w.y * s.y;
                    acc[r] += w.z * s.z; acc[r] += w.w * s.w;
                }
            }
#pragma unroll
            for (int r = 0; r < R; ++r) {
                float zh = szh[r][o], xh = sxh[r][o];
                float th = acc[r] * zh + (1.f - acc[r]) * xh;
                stemp[r][n][o] = th;
                float xv = sx[r][o], mv = scat[r][C + o];
                float ind = ((xv <= th) ? 1.f : 0.f) - q;
                ql += fabsf((th - xv) * mv * ind);
                ens[(((size_t)(b0 + r) * NUM + n) * T + t) * C + o] =
                    mv * xv + (1.f - mv) * th;
            }
        }
        l_acc += ql * (1.f / NUM);
        __syncthreads();

        // P5: mean over NUM; loss4; c_c (into sv); imp write
        if (tid < R * C) {
            int r = tid / C, o = tid % C;
            float s = 0.f;
#pragma unroll
            for (int n = 0; n < NUM; ++n) s += stemp[r][n][o];
            float tm = s * (1.f / NUM);
            float xv = sx[r][o], mv = scat[r][C + o];
            l_acc += fabsf(xv - tm) * mv;
            float cc = mv * xv + (1.f - mv) * tm;
            sv[r][o] = cc;
            imp[((size_t)(b0 + r) * T + t) * C + o] = cc;
        }
        loss += l_acc * inv_msum;
        __syncthreads();   // also protects sbig reuse (temp -> gates)

        // P6: gates = [c_c|mt|h] . Wg + bias — 50 coalesced dwordx4 per thread
        {
            int j = tid;  // NTHR == G4
            float acc[R];
            float bv = gb[j];
#pragma unroll
            for (int r = 0; r < R; ++r) acc[r] = bv;
            const float4* W = Wg4 + j;
            for (int kb = 0; kb < KG4 / 4; ++kb) {
                float4 w = W[kb * G4];
#pragma unroll
                for (int r = 0; r < R; ++r) {
                    float4 s = *(const float4*)&sv[r][4 * kb];
                    acc[r] += w.x * s.x; acc[r] += w.y * s.y;
                    acc[r] += w.z * s.z; acc[r] += w.w * s.w;
                }
            }
#pragma unroll
            for (int r = 0; r < R; ++r) sg[r][j] = acc[r];
        }
        __syncthreads();

        // P7: LSTM cell update
        for (int i = tid; i < R * H; i += NTHR) {
            int r = i / H, jj = i % H;
            float ig = sg[r][jj], fg = sg[r][H + jj];
            float gg = sg[r][2 * H + jj], og = sg[r][3 * H + jj];
            float si = 1.f / (1.f + __expf(-ig));
            float sf = 1.f / (1.f + __expf(-fg));
            float so = 1.f / (1.f + __expf(-og));
            float tg = tanhf(gg);
            float cv = sf * scl[r][jj] + si * tg;
            scl[r][jj] = cv;
            sh[r][jj] = so * tanhf(cv);
        }
        __syncthreads();
    }

    // final loss reduction (reuse sbig)
    float* red = sbig;
    red[tid] = loss;
    __syncthreads();
    for (int off = NTHR / 2; off > 0; off >>= 1) {
        if (tid < off) red[tid] += red[tid + off];
        __syncthreads();
    }
    if (tid == 0) atomicAdd(out, red[0] * (1.f / (float)T));
}

extern "C" void kernel_launch(void* const* d_in, const int* in_sizes, int n_in,
                              void* d_out, int out_size, void* d_ws, size_t ws_size,
                              hipStream_t stream) {
    const float* x      = (const float*)d_in[0];
    const float* mask   = (const float*)d_in[1];
    const float* delta  = (const float*)d_in[2];
    const float* w_dh   = (const float*)d_in[3];
    const float* b_dh   = (const float*)d_in[4];
    const float* w_dx   = (const float*)d_in[5];
    const float* b_dx   = (const float*)d_in[6];
    const float* w_hr   = (const float*)d_in[7];
    const float* b_hr   = (const float*)d_in[8];
    const float* w_fr   = (const float*)d_in[9];
    const float* b_fr   = (const float*)d_in[10];
    const float* w_comb = (const float*)d_in[11];
    const float* b_comb = (const float*)d_in[12];
    const float* w_ih   = (const float*)d_in[13];
    const float* w_hh   = (const float*)d_in[14];
    const float* b_ih   = (const float*)d_in[15];
    const float* b_hh   = (const float*)d_in[16];
    float* out = (float*)d_out;
    float* ws  = (float*)d_ws;

    prep_kernel<<<64, 256, 0, stream>>>(mask, w_dh, w_hr, w_fr, w_comb, w_ih, w_hh,
                                        b_ih, b_hh, ws, out);
    main_kernel<<<NBLK, NTHR, 0, stream>>>(x, mask, delta, b_dh, w_dx, b_dx, b_hr,
                                           b_fr, b_comb, ws, out);
}

// Round 5
// 1577.623 us; speedup vs baseline: 1.5467x; 1.5467x over previous
//
#include <hip/hip_runtime.h>
#include <math.h>

#define B 2048
#define T 48
#define C 35
#define NUM 19
#define H 128
#define R 4              // batch rows per block
#define NBLK (B / R)     // 512 blocks
#define NTHR 256         // 4 waves = 1 wave/SIMD -> fine-grained CU packing
#define K2C 70           // 2*C
#define K2C4 72          // padded to mult of 4
#define KG 198           // 2*C + H
#define KG4 200          // padded
#define C4 36            // C padded
#define G4 512           // 4*H
#define NO 665           // NUM*C

// ws layout (floats) — weight panels packed as k-blocked float4 tiles:
// w4[(k>>2)*(OUT*4) + out*4 + (k&3)]
#define WS_MSUM 0                        // [48] inv msum (padded to 64)
#define WS_WGT4 64                       // [KG4/4][G4][4] gates weights
#define WS_GB   (WS_WGT4 + KG4 * G4)     // [512] b_ih + b_hh
#define WS_WCT4 (WS_GB + G4)             // [K2C4/4][NO][4] w_comb
#define WS_WDH4 (WS_WCT4 + K2C4 * NO)    // [C4/4][H][4] w_dh
#define WS_WHR4 (WS_WDH4 + C4 * H)       // [H/4][C][4] w_hr
#define WS_FRT  (WS_WHR4 + H * C)        // [35][35] fr_w^T (zero diag), scalar

__global__ __launch_bounds__(256)
void prep_kernel(const float* __restrict__ mask,
                 const float* __restrict__ w_dh,
                 const float* __restrict__ w_hr,
                 const float* __restrict__ w_fr,
                 const float* __restrict__ w_comb,
                 const float* __restrict__ w_ih,
                 const float* __restrict__ w_hh,
                 const float* __restrict__ b_ih,
                 const float* __restrict__ b_hh,
                 float* __restrict__ ws,
                 float* __restrict__ out) {
    int blk = blockIdx.x, tid = threadIdx.x;
    if (blk < T) {
        // msum for timestep t = blk (sum over full batch)
        float s = 0.f;
        for (int i = tid; i < B * C; i += 256) {
            int b = i / C, c = i % C;
            s += mask[((size_t)b * T + blk) * C + c];
        }
        __shared__ float red[256];
        red[tid] = s;
        __syncthreads();
        for (int off = 128; off > 0; off >>= 1) {
            if (tid < off) red[tid] += red[tid + off];
            __syncthreads();
        }
        if (tid == 0) ws[WS_MSUM + blk] = 1.0f / (red[0] + 1e-5f);
    } else {
        int gt = (blk - T) * 256 + tid;  // 0..4095
        if (gt == 0) out[0] = 0.f;       // zero the loss accumulator
        // gates weights: k in [0,200), j in [0,512)
        for (int i = gt; i < KG4 * G4; i += 4096) {
            int k = i / G4, j = i % G4;
            float v = 0.f;
            if (k < K2C)      v = w_ih[j * K2C + k];
            else if (k < KG)  v = w_hh[j * H + (k - K2C)];
            ws[WS_WGT4 + (k >> 2) * (G4 * 4) + j * 4 + (k & 3)] = v;
        }
        for (int j = gt; j < G4; j += 4096) ws[WS_GB + j] = b_ih[j] + b_hh[j];
        // w_comb: f in [0,72), idx in [0,665)
        for (int i = gt; i < K2C4 * NO; i += 4096) {
            int f = i / NO, idx = i % NO;
            float v = (f < K2C) ? w_comb[idx * K2C + f] : 0.f;
            ws[WS_WCT4 + (f >> 2) * (NO * 4) + idx * 4 + (f & 3)] = v;
        }
        // w_dh: k in [0,36), j in [0,128)
        for (int i = gt; i < C4 * H; i += 4096) {
            int k = i / H, j = i % H;
            float v = (k < C) ? w_dh[j * C + k] : 0.f;
            ws[WS_WDH4 + (k >> 2) * (H * 4) + j * 4 + (k & 3)] = v;
        }
        // w_hr: k in [0,128), o in [0,35)
        for (int i = gt; i < H * C; i += 4096) {
            int k = i / C, o = i % C;
            ws[WS_WHR4 + (k >> 2) * (C * 4) + o * 4 + (k & 3)] = w_hr[o * H + k];
        }
        for (int i = gt; i < C * C; i += 4096) {
            int k = i / C, o = i % C;
            ws[WS_FRT + i] = (k == o) ? 0.f : w_fr[o * C + k];
        }
    }
}

__global__ __launch_bounds__(NTHR, 2)
void main_kernel(const float* __restrict__ x, const float* __restrict__ mask,
                 const float* __restrict__ delta,
                 const float* __restrict__ b_dh, const float* __restrict__ w_dx,
                 const float* __restrict__ b_dx, const float* __restrict__ b_hr,
                 const float* __restrict__ b_fr, const float* __restrict__ b_comb,
                 const float* __restrict__ ws, float* __restrict__ out) {
    __shared__ float sh[R][H];       // hidden state
    __shared__ float scl[R][H];      // cell state
    __shared__ float sx[R][C];
    __shared__ float sdt[R][C4];     // delta (padded, [35]=0)
    __shared__ float scat[R][K2C4];  // [gamma_x | mask | 0,0]
    __shared__ float sv[R][KG4];     // [c_c | mask | h | 0,0] — P6 input vector
    __shared__ float sxh[R][C];
    __shared__ float sxc[R][C];
    __shared__ float szh[R][C];
    __shared__ float sbig[R * NUM * C];  // aliased: temp_h (P4-P5) / gates (P6-P7) / reduce

    float (*stemp)[NUM][C] = (float (*)[NUM][C])sbig;
    float (*sg)[G4] = (float (*)[G4])sbig;

    const int tid = threadIdx.x;
    const int b0 = blockIdx.x * R;
    const float4* Wg4 = (const float4*)(ws + WS_WGT4);
    const float*  gb  = ws + WS_GB;
    const float4* Wc4 = (const float4*)(ws + WS_WCT4);
    const float4* Wd4 = (const float4*)(ws + WS_WDH4);
    const float4* Wr4 = (const float4*)(ws + WS_WHR4);
    const float*  frT = ws + WS_FRT;
    float* imp = out + 1;
    float* ens = out + 1 + (size_t)B * T * C;

    for (int i = tid; i < R * H; i += NTHR) { ((float*)sh)[i] = 0.f; ((float*)scl)[i] = 0.f; }
    if (tid < R) {  // zero the pads once; never rewritten
        sdt[tid][C] = 0.f;
        scat[tid][K2C] = 0.f; scat[tid][K2C + 1] = 0.f;
        sv[tid][KG] = 0.f; sv[tid][KG + 1] = 0.f;
    }
    float loss = 0.f;
    __syncthreads();

    for (int t = 0; t < T; ++t) {
        const float inv_msum = ws[WS_MSUM + t];

        // P0: load x, mask, delta; gamma_x
        for (int i = tid; i < R * C; i += NTHR) {
            int r = i / C, c = i % C;
            size_t gi = ((size_t)(b0 + r) * T + t) * C + c;
            float xv = x[gi], mv = mask[gi], dv = delta[gi];
            sx[r][c] = xv; sdt[r][c] = dv;
            scat[r][c] = __expf(-fmaxf(dv * w_dx[c * C + c] + b_dx[c], 0.f));
            scat[r][C + c] = mv;
            sv[r][C + c] = mv;
        }
        __syncthreads();

        // P1: gamma_h, decay h; also mirror h into sv for P6
        for (int i = tid; i < R * H; i += NTHR) {
            int r = i / H, j = i % H;
            float d = b_dh[j];
            const float4* W = Wd4 + j;
            for (int kb = 0; kb < C4 / 4; ++kb) {
                float4 w = W[kb * H];
                float4 s = *(const float4*)&sdt[r][4 * kb];
                d += w.x * s.x; d += w.y * s.y; d += w.z * s.z; d += w.w * s.w;
            }
            float hv = sh[r][j] * __expf(-fmaxf(d, 0.f));
            sh[r][j] = hv;
            sv[r][K2C + j] = hv;
        }
        __syncthreads();

        // P2: x_h = h @ w_hr^T + b_hr; loss1; x_c
        float l_acc = 0.f;
        if (tid < R * C) {
            int r = tid / C, o = tid % C;
            float d = b_hr[o];
            const float4* W = Wr4 + o;
            for (int kb = 0; kb < H / 4; ++kb) {
                float4 w = W[kb * C];
                float4 s = *(const float4*)&sh[r][4 * kb];
                d += w.x * s.x; d += w.y * s.y; d += w.z * s.z; d += w.w * s.w;
            }
            float xv = sx[r][o], mv = scat[r][C + o];
            sxh[r][o] = d;
            l_acc += fabsf(xv - d) * mv;
            sxc[r][o] = mv * xv + (1.f - mv) * d;
        }
        __syncthreads();

        // P3: z_h = x_c @ fr_w^T + b_fr; loss2
        if (tid < R * C) {
            int r = tid / C, o = tid % C;
            float d = b_fr[o];
            for (int k = 0; k < C; ++k) d += frT[k * C + o] * sxc[r][k];
            szh[r][o] = d;
            l_acc += fabsf(sx[r][o] - d) * scat[r][C + o];
        }
        __syncthreads();

        // P4: alpha GEMM -> temp_h, quantile loss, ens write
        // 3 outputs per thread (idx, idx+256, idx+512) share the scat reads.
        float ql = 0.f;
        {
            const int i0 = tid, i1 = tid + 256, i2 = tid + 512;
            float acc[3][R];
            float bc0 = b_comb[i0];
            float bc1 = b_comb[i1];
            float bc2 = (i2 < NO) ? b_comb[i2] : 0.f;
#pragma unroll
            for (int r = 0; r < R; ++r) { acc[0][r] = bc0; acc[1][r] = bc1; acc[2][r] = bc2; }
            for (int fb = 0; fb < K2C4 / 4; ++fb) {
                // i2 may read past NO within the packed ws region — harmless, discarded.
                float4 w0 = Wc4[fb * NO + i0];
                float4 w1 = Wc4[fb * NO + i1];
                float4 w2 = Wc4[fb * NO + i2];
#pragma unroll
                for (int r = 0; r < R; ++r) {
                    float4 s = *(const float4*)&scat[r][4 * fb];
                    acc[0][r] += w0.x * s.x; acc[0][r] += w0.y * s.y;
                    acc[0][r] += w0.z * s.z; acc[0][r] += w0.w * s.w;
                    acc[1][r] += w1.x * s.x; acc[1][r] += w1.y * s.y;
                    acc[1][r] += w1.z * s.z; acc[1][r] += w1.w * s.w;
                    acc[2][r] += w2.x * s.x; acc[2][r] += w2.y * s.y;
                    acc[2][r] += w2.z * s.z; acc[2][r] += w2.w * s.w;
                }
            }
#pragma unroll
            for (int m = 0; m < 3; ++m) {
                int idx = tid + 256 * m;
                if (idx < NO) {
                    int n = idx / C, o = idx % C;
                    float q = 0.05f * (float)(n + 1);
#pragma unroll
                    for (int r = 0; r < R; ++r) {
                        float zh = szh[r][o], xh = sxh[r][o];
                        float th = acc[m][r] * zh + (1.f - acc[m][r]) * xh;
                        stemp[r][n][o] = th;
                        float xv = sx[r][o], mv = scat[r][C + o];
                        float ind = ((xv <= th) ? 1.f : 0.f) - q;
                        ql += fabsf((th - xv) * mv * ind);
                        ens[(((size_t)(b0 + r) * NUM + n) * T + t) * C + o] =
                            mv * xv + (1.f - mv) * th;
                    }
                }
            }
        }
        l_acc += ql * (1.f / NUM);
        __syncthreads();

        // P5: mean over NUM; loss4; c_c (into sv); imp write
        if (tid < R * C) {
            int r = tid / C, o = tid % C;
            float s = 0.f;
#pragma unroll
            for (int n = 0; n < NUM; ++n) s += stemp[r][n][o];
            float tm = s * (1.f / NUM);
            float xv = sx[r][o], mv = scat[r][C + o];
            l_acc += fabsf(xv - tm) * mv;
            float cc = mv * xv + (1.f - mv) * tm;
            sv[r][o] = cc;
            imp[((size_t)(b0 + r) * T + t) * C + o] = cc;
        }
        loss += l_acc * inv_msum;
        __syncthreads();   // also protects sbig reuse (temp -> gates)

        // P6: gates = [c_c|mt|h] . Wg + bias — 2 gate columns per thread share sv reads
        {
            const int j0 = tid, j1 = tid + 256;
            float a0[R], a1[R];
            float bv0 = gb[j0], bv1 = gb[j1];
#pragma unroll
            for (int r = 0; r < R; ++r) { a0[r] = bv0; a1[r] = bv1; }
            for (int kb = 0; kb < KG4 / 4; ++kb) {
                float4 w0 = Wg4[kb * G4 + j0];
                float4 w1 = Wg4[kb * G4 + j1];
#pragma unroll
                for (int r = 0; r < R; ++r) {
                    float4 s = *(const float4*)&sv[r][4 * kb];
                    a0[r] += w0.x * s.x; a0[r] += w0.y * s.y;
                    a0[r] += w0.z * s.z; a0[r] += w0.w * s.w;
                    a1[r] += w1.x * s.x; a1[r] += w1.y * s.y;
                    a1[r] += w1.z * s.z; a1[r] += w1.w * s.w;
                }
            }
#pragma unroll
            for (int r = 0; r < R; ++r) { sg[r][j0] = a0[r]; sg[r][j1] = a1[r]; }
        }
        __syncthreads();

        // P7: LSTM cell update
        for (int i = tid; i < R * H; i += NTHR) {
            int r = i / H, jj = i % H;
            float ig = sg[r][jj], fg = sg[r][H + jj];
            float gg = sg[r][2 * H + jj], og = sg[r][3 * H + jj];
            float si = 1.f / (1.f + __expf(-ig));
            float sf = 1.f / (1.f + __expf(-fg));
            float so = 1.f / (1.f + __expf(-og));
            float tg = tanhf(gg);
            float cv = sf * scl[r][jj] + si * tg;
            scl[r][jj] = cv;
            sh[r][jj] = so * tanhf(cv);
        }
        __syncthreads();
    }

    // final loss reduction (reuse sbig)
    float* red = sbig;
    red[tid] = loss;
    __syncthreads();
    for (int off = NTHR / 2; off > 0; off >>= 1) {
        if (tid < off) red[tid] += red[tid + off];
        __syncthreads();
    }
    if (tid == 0) atomicAdd(out, red[0] * (1.f / (float)T));
}

extern "C" void kernel_launch(void* const* d_in, const int* in_sizes, int n_in,
                              void* d_out, int out_size, void* d_ws, size_t ws_size,
                              hipStream_t stream) {
    const float* x      = (const float*)d_in[0];
    const float* mask   = (const float*)d_in[1];
    const float* delta  = (const float*)d_in[2];
    const float* w_dh   = (const float*)d_in[3];
    const float* b_dh   = (const float*)d_in[4];
    const float* w_dx   = (const float*)d_in[5];
    const float* b_dx   = (const float*)d_in[6];
    const float* w_hr   = (const float*)d_in[7];
    const float* b_hr   = (const float*)d_in[8];
    const float* w_fr   = (const float*)d_in[9];
    const float* b_fr   = (const float*)d_in[10];
    const float* w_comb = (const float*)d_in[11];
    const float* b_comb = (const float*)d_in[12];
    const float* w_ih   = (const float*)d_in[13];
    const float* w_hh   = (const float*)d_in[14];
    const float* b_ih   = (const float*)d_in[15];
    const float* b_hh   = (const float*)d_in[16];
    float* out = (float*)d_out;
    float* ws  = (float*)d_ws;

    prep_kernel<<<64, 256, 0, stream>>>(mask, w_dh, w_hr, w_fr, w_comb, w_ih, w_hh,
                                        b_ih, b_hh, ws, out);
    main_kernel<<<NBLK, NTHR, 0, stream>>>(x, mask, delta, b_dh, w_dx, b_dx, b_hr,
                                           b_fr, b_comb, ws, out);
}